// Round 8
// baseline (587.159 us; speedup 1.0000x reference)
//
#include <hip/hip_runtime.h>
#include <math.h>

#define N_NODES 100000
#define N_EDGES 400000
#define HID 128
#define HEADS 4
#define OUT_C 64
#define HD 256   // HEADS*OUT_C
#define SCAN_CHUNK 1024
#define NB_SCAN ((N_NODES + SCAN_CHUNK - 1) / SCAN_CHUNK)   // 98

typedef __attribute__((ext_vector_type(8))) short bf16x8;   // 8 bf16 = 4 VGPRs
typedef __attribute__((ext_vector_type(4))) float f32x4;

// fp32 -> bf16 round-to-nearest-even
__device__ __forceinline__ unsigned short fbf(float f) {
    unsigned u = __float_as_uint(f);
    unsigned r = (u + 0x7fffu + ((u >> 16) & 1u)) >> 16;
    return (unsigned short)r;
}
__device__ __forceinline__ float bf2f(unsigned short u) {
    return __uint_as_float(((unsigned)u) << 16);
}

// ---------- K0: zero deg + cursor ----------
__global__ __launch_bounds__(256) void init_zero(int* __restrict__ deg,
                                                 int* __restrict__ cursor) {
    int i = blockIdx.x * 256 + threadIdx.x;
    if (i < N_NODES) { deg[i] = 0; cursor[i] = 0; }
}

// ---------- CSR build: degree count ----------
__global__ __launch_bounds__(256) void k_deg(const int* __restrict__ ei,
                                             int* __restrict__ deg) {
    int e = blockIdx.x * 256 + threadIdx.x;
    if (e < N_EDGES) atomicAdd(&deg[ei[N_EDGES + e]], 1);
}

// ---------- scan 1 ----------
__global__ __launch_bounds__(256) void k_scan1(const int* __restrict__ deg,
                                               int* __restrict__ rp,
                                               int* __restrict__ bsum) {
    __shared__ int ts[256];
    int b = blockIdx.x, t = threadIdx.x;
    int base = b * SCAN_CHUNK + t * 4;
    int vv[4];
    int s = 0;
#pragma unroll
    for (int i = 0; i < 4; ++i) {
        int d = (base + i < N_NODES) ? deg[base + i] : 0;
        vv[i] = s;
        s += d;
    }
    ts[t] = s;
    __syncthreads();
    for (int off = 1; off < 256; off <<= 1) {
        int x = (t >= off) ? ts[t - off] : 0;
        __syncthreads();
        ts[t] += x;
        __syncthreads();
    }
    int ex = ts[t] - s;
#pragma unroll
    for (int i = 0; i < 4; ++i)
        if (base + i < N_NODES) rp[base + i] = ex + vv[i];
    if (t == 255) bsum[b] = ts[255];
}

// ---------- scan 2 ----------
__global__ __launch_bounds__(256) void k_scan2(int* __restrict__ bsum) {
    __shared__ int ts[256];
    int t = threadIdx.x;
    int v = (t < NB_SCAN) ? bsum[t] : 0;
    ts[t] = v;
    __syncthreads();
    for (int off = 1; off < 256; off <<= 1) {
        int x = (t >= off) ? ts[t - off] : 0;
        __syncthreads();
        ts[t] += x;
        __syncthreads();
    }
    if (t < NB_SCAN) bsum[t] = ts[t] - v;
}

// ---------- scan 3 ----------
__global__ __launch_bounds__(256) void k_scan3(int* __restrict__ rp,
                                               const int* __restrict__ bsum) {
    int i = blockIdx.x * 256 + threadIdx.x;
    if (i < N_NODES) rp[i] += bsum[i / SCAN_CHUNK];
}

// ---------- bucket: fill csr_src / csr_dst / csr_eid ----------
__global__ __launch_bounds__(256) void k_bucket(const int* __restrict__ ei,
                                                const int* __restrict__ rp,
                                                int* __restrict__ cursor,
                                                int* __restrict__ csr_src,
                                                int* __restrict__ csr_dst,
                                                int* __restrict__ csr_eid) {
    int e = blockIdx.x * 256 + threadIdx.x;
    if (e >= N_EDGES) return;
    int src = ei[e];
    int d   = ei[N_EDGES + e];
    int idx = atomicAdd(&cursor[d], 1);
    int s   = rp[d] + idx;
    csr_src[s] = src;
    csr_dst[s] = d;
    csr_eid[s] = e;
}

// ---------- pack 4 projection weights [128,256] -> [z][kt][nt][lane][8] bf16 ----------
__global__ __launch_bounds__(256) void pack_wg(
    const float* __restrict__ Wq, const float* __restrict__ Wk,
    const float* __restrict__ Wv, const float* __restrict__ Ws,
    unsigned short* __restrict__ Wp) {
    int i = blockIdx.x * 256 + threadIdx.x;   // 4*4*16*64 = 16384
    if (i >= 16384) return;
    int lane = i & 63, nt = (i >> 6) & 15, kt = (i >> 10) & 3, z = i >> 12;
    const float* W = (z == 0) ? Wq : (z == 1) ? Wk : (z == 2) ? Wv : Ws;
    int q = lane >> 4, c = lane & 15;
#pragma unroll
    for (int j = 0; j < 8; ++j)
        Wp[i * 8 + j] = fbf(W[(kt * 32 + q * 8 + j) * HD + nt * 16 + c]);
}

// ---------- pack W1 [512,128] into MFMA B-frag order [kt][nt][lane][8] bf16 ----------
__global__ __launch_bounds__(256) void pack_w1(const float* __restrict__ W1,
                                               unsigned short* __restrict__ W1p) {
    int i = blockIdx.x * 256 + threadIdx.x;   // 16*8*64 = 8192
    if (i >= 8192) return;
    int lane = i & 63, nt = (i >> 6) & 7, kt = i >> 9;
    int q = lane >> 4, c = lane & 15;
#pragma unroll
    for (int j = 0; j < 8; ++j)
        W1p[i * 8 + j] = fbf(W1[(kt * 32 + q * 8 + j) * 128 + nt * 16 + c]);
}

// ---------- pack W2 [128,64] -> [kt][nt][lane][8] bf16 ----------
__global__ __launch_bounds__(256) void pack_w2(const float* __restrict__ W2,
                                               unsigned short* __restrict__ W2p) {
    int i = blockIdx.x * 256 + threadIdx.x;   // 4*4*64 = 1024
    if (i >= 1024) return;
    int lane = i & 63, nt = (i >> 6) & 3, kt = i >> 8;
    int q = lane >> 4, c = lane & 15;
#pragma unroll
    for (int j = 0; j < 8; ++j)
        W2p[i * 8 + j] = fbf(W2[(kt * 32 + q * 8 + j) * 64 + nt * 16 + c]);
}

// ---------- K1: projection GEMM (MFMA bf16), z split across grid.y ----------
// grid (1563, 4): blockIdx.y picks which of q/k/v/skip this block computes.
// 4x the block-level parallelism of R7; redundant x+mem reads are L3-absorbed.
// Output slab ALIASES the As buffer (union) -> LDS 35 KB -> 4 blocks/CU.
__global__ __launch_bounds__(256) void gemm_proj(
    const float* __restrict__ x, const float* __restrict__ mem,
    const unsigned short* __restrict__ Wp,
    const float* __restrict__ bq, const float* __restrict__ bk,
    const float* __restrict__ bv, const float* __restrict__ bs,
    unsigned short* __restrict__ Q, unsigned short* __restrict__ K,
    unsigned short* __restrict__ V, unsigned short* __restrict__ S)
{
    __shared__ __align__(16) short sh[4 * 64 * 68];   // 34.8 KB union:
    short* As   = sh;                                  //   As  [64][136] (first 17.4 KB)
    short* Slab = sh;                                  //   Slab 4x[64][68] (all of it)

    const int t = threadIdx.x;
    const int w = t >> 6, l = t & 63;
    const int q = l >> 4, c = l & 15;
    const int m0 = blockIdx.x * 64;
    const int z  = blockIdx.y;

    // stage A = bf16(x+mem)[m0..m0+64, 0..128)
    {
        const float4* x4 = (const float4*)x;
        const float4* m4 = (const float4*)mem;
#pragma unroll
        for (int j = 0; j < 8; ++j) {
            int idx = t + j * 256;       // 2048 float4 chunks
            int row = idx >> 5, c4 = idx & 31;
            int gr  = m0 + row;
            ushort4 hv = make_ushort4(0, 0, 0, 0);
            if (gr < N_NODES) {
                float4 a = x4[(size_t)gr * 32 + c4];
                float4 b = m4[(size_t)gr * 32 + c4];
                hv = make_ushort4(fbf(a.x + b.x), fbf(a.y + b.y),
                                  fbf(a.z + b.z), fbf(a.w + b.w));
            }
            *(ushort4*)&As[row * 136 + c4 * 4] = hv;
        }
    }
    __syncthreads();

    const float* bz = (z == 0) ? bq : (z == 1) ? bk : (z == 2) ? bv : bs;
    unsigned short* Oz = (z == 0) ? Q : (z == 1) ? K : (z == 2) ? V : S;

    f32x4 acc[4][4];
#pragma unroll
    for (int mt = 0; mt < 4; ++mt)
#pragma unroll
        for (int nt = 0; nt < 4; ++nt) acc[mt][nt] = (f32x4){0.f, 0.f, 0.f, 0.f};

#pragma unroll
    for (int kt = 0; kt < 4; ++kt) {
        bf16x8 af[4];
#pragma unroll
        for (int mt = 0; mt < 4; ++mt)
            af[mt] = *(const bf16x8*)&As[(mt * 16 + c) * 136 + kt * 32 + q * 8];
#pragma unroll
        for (int nt = 0; nt < 4; ++nt) {
            int ntg = w * 4 + nt;
            bf16x8 bv8 = *(const bf16x8*)&Wp[(size_t)(((z * 4 + kt) * 16 + ntg) * 64 + l) * 8];
#pragma unroll
            for (int mt = 0; mt < 4; ++mt)
                acc[mt][nt] = __builtin_amdgcn_mfma_f32_16x16x32_bf16(af[mt], bv8, acc[mt][nt], 0, 0, 0);
        }
    }
    __syncthreads();   // all As reads done; Slab aliases As

    // epilogue: bias -> wave-private slab, then wide coalesced stores
    short* slab = &Slab[w * 64 * 68];
#pragma unroll
    for (int nt = 0; nt < 4; ++nt) {
        float bb = bz[w * 64 + nt * 16 + c];
#pragma unroll
        for (int mt = 0; mt < 4; ++mt)
#pragma unroll
            for (int r = 0; r < 4; ++r)
                slab[(mt * 16 + q * 4 + r) * 68 + nt * 16 + c] =
                    (short)fbf(acc[mt][nt][r] + bb);
    }
    const int srow = l >> 3;   // 0..7
    const int schk = l & 7;    // 0..7
#pragma unroll
    for (int j = 0; j < 8; ++j) {
        int row = j * 8 + srow;
        int gr = m0 + row;
        if (gr < N_NODES)
            *(bf16x8*)&Oz[(size_t)gr * HD + w * 64 + schk * 8] =
                *(const bf16x8*)&slab[row * 68 + schk * 8];
    }
}

// ---------- K2: fused attention, online softmax, one wave per node ----------
__global__ __launch_bounds__(256) void k_attn(
    const int* __restrict__ rp, const int* __restrict__ deg,
    const int* __restrict__ csr_src,
    const unsigned short* __restrict__ Q, const unsigned short* __restrict__ K,
    const unsigned short* __restrict__ V, const unsigned short* __restrict__ S,
    unsigned short* __restrict__ out)
{
    int node = blockIdx.x * 4 + (threadIdx.x >> 6);
    int l = threadIdx.x & 63;
    if (node >= N_NODES) return;
    int start = rp[node];
    int cnt   = deg[node];

    float q0, q1, q2, q3;
    {
        ushort4 u = *(const ushort4*)&Q[(size_t)node * HD + l * 4];
        q0 = bf2f(u.x); q1 = bf2f(u.y); q2 = bf2f(u.z); q3 = bf2f(u.w);
    }

    float m = -1e30f, d = 0.f;
    float a0 = 0.f, a1 = 0.f, a2 = 0.f, a3 = 0.f;

    for (int i = 0; i < cnt; ++i) {
        int src = csr_src[start + i];
        ushort4 ku = *(const ushort4*)&K[(size_t)src * HD + l * 4];
        float s = q0 * bf2f(ku.x) + q1 * bf2f(ku.y) + q2 * bf2f(ku.z) + q3 * bf2f(ku.w);
        s += __shfl_xor(s, 1);
        s += __shfl_xor(s, 2);
        s += __shfl_xor(s, 4);
        s += __shfl_xor(s, 8);
        s *= 0.125f;                       // 1/sqrt(64)

        float mn    = fmaxf(m, s);
        float scale = __expf(m - mn);      // first iter: exp(-huge)=0
        float e     = __expf(s - mn);
        d = d * scale + e;
        ushort4 vu = *(const ushort4*)&V[(size_t)src * HD + l * 4];
        a0 = a0 * scale + e * bf2f(vu.x);
        a1 = a1 * scale + e * bf2f(vu.y);
        a2 = a2 * scale + e * bf2f(vu.z);
        a3 = a3 * scale + e * bf2f(vu.w);
        m = mn;
    }

    float inv = 1.f / (d + 1e-16f);
    ushort4 su = *(const ushort4*)&S[(size_t)node * HD + l * 4];
    ushort4 ov = make_ushort4(fbf(bf2f(su.x) + a0 * inv),
                              fbf(bf2f(su.y) + a1 * inv),
                              fbf(bf2f(su.z) + a2 * inv),
                              fbf(bf2f(su.w) + a3 * inv));
    *(ushort4*)&out[(size_t)node * HD + l * 4] = ov;
}

// ---------- K5: MFMA rating MLP, 64 edges/block, CSR (dst-sorted) order ----------
__global__ __launch_bounds__(256) void edge_mlp_mfma(
    const int* __restrict__ csr_src, const int* __restrict__ csr_dst,
    const int* __restrict__ csr_eid,
    const unsigned short* __restrict__ outb,
    const unsigned short* __restrict__ W1p, const float* __restrict__ b1,
    const unsigned short* __restrict__ W2p, const float* __restrict__ b2,
    const float* __restrict__ W3, const float* __restrict__ b3,
    float* __restrict__ rating)
{
    __shared__ __align__(16) char lds_raw[64 * 264 * 2];   // inter bf16 [64][264]; later h2 f32 [64][65]
    __shared__ __align__(16) short h1_s[64 * 136];
    short* inter_s = (short*)lds_raw;
    float* h2_s    = (float*)lds_raw;

    const int t = threadIdx.x;
    const int w = t >> 6, l = t & 63;
    const int q = l >> 4, c = l & 15;
    const int e0 = blockIdx.x * 64;

    f32x4 acc[8];
#pragma unroll
    for (int i = 0; i < 8; ++i) acc[i] = (f32x4){0.f, 0.f, 0.f, 0.f};

    for (int p = 0; p < 2; ++p) {
        const int* idxp = (p == 0) ? csr_src : csr_dst;
#pragma unroll
        for (int j = 0; j < 8; ++j) {
            int idx = t + j * 256;           // 2048 chunks of 16 B
            int row = idx >> 5, c4 = idx & 31;
            int node = idxp[e0 + row];
            *(bf16x8*)&inter_s[row * 264 + c4 * 8] =
                *(const bf16x8*)&outb[(size_t)node * HD + c4 * 8];
        }
        __syncthreads();
#pragma unroll
        for (int kt = 0; kt < 8; ++kt) {
            bf16x8 av = *(const bf16x8*)&inter_s[(w * 16 + c) * 264 + kt * 32 + q * 8];
#pragma unroll
            for (int nt = 0; nt < 8; ++nt) {
                bf16x8 bv = *(const bf16x8*)&W1p[(size_t)(((p * 8 + kt) * 8 + nt) * 64 + l) * 8];
                acc[nt] = __builtin_amdgcn_mfma_f32_16x16x32_bf16(av, bv, acc[nt], 0, 0, 0);
            }
        }
        __syncthreads();
    }

#pragma unroll
    for (int nt = 0; nt < 8; ++nt) {
        float bv = b1[nt * 16 + c];
#pragma unroll
        for (int r = 0; r < 4; ++r)
            h1_s[(w * 16 + q * 4 + r) * 136 + nt * 16 + c] =
                (short)fbf(fmaxf(acc[nt][r] + bv, 0.f));
    }
    __syncthreads();

    f32x4 acc2[4];
#pragma unroll
    for (int i = 0; i < 4; ++i) acc2[i] = (f32x4){0.f, 0.f, 0.f, 0.f};
#pragma unroll
    for (int kt = 0; kt < 4; ++kt) {
        bf16x8 av = *(const bf16x8*)&h1_s[(w * 16 + c) * 136 + kt * 32 + q * 8];
#pragma unroll
        for (int nt = 0; nt < 4; ++nt) {
            bf16x8 bv = *(const bf16x8*)&W2p[(size_t)((kt * 4 + nt) * 64 + l) * 8];
            acc2[nt] = __builtin_amdgcn_mfma_f32_16x16x32_bf16(av, bv, acc2[nt], 0, 0, 0);
        }
    }
    __syncthreads();

#pragma unroll
    for (int nt = 0; nt < 4; ++nt) {
        float bv = b2[nt * 16 + c];
#pragma unroll
        for (int r = 0; r < 4; ++r)
            h2_s[(w * 16 + q * 4 + r) * 65 + nt * 16 + c] = fmaxf(acc2[nt][r] + bv, 0.f);
    }
    __syncthreads();

    if (t < 64) {
        float a = b3[0];
#pragma unroll 8
        for (int kk = 0; kk < 64; ++kk)
            a += h2_s[t * 65 + kk] * W3[kk];
        rating[csr_eid[e0 + t]] = 4.f / (1.f + __expf(-a)) + 1.f;
    }
}

extern "C" void kernel_launch(void* const* d_in, const int* in_sizes, int n_in,
                              void* d_out, int out_size, void* d_ws, size_t ws_size,
                              hipStream_t stream) {
    const int*   ei  = (const int*)d_in[0];    // [2, E]
    const float* x   = (const float*)d_in[2];
    const float* mem = (const float*)d_in[3];
    const float* Wq  = (const float*)d_in[4];
    const float* bq  = (const float*)d_in[5];
    const float* Wk  = (const float*)d_in[6];
    const float* bk  = (const float*)d_in[7];
    const float* Wv  = (const float*)d_in[8];
    const float* bv  = (const float*)d_in[9];
    const float* Ws  = (const float*)d_in[10];
    const float* bs  = (const float*)d_in[11];
    const float* W1  = (const float*)d_in[12];
    const float* b1  = (const float*)d_in[13];
    const float* W2  = (const float*)d_in[14];
    const float* b2  = (const float*)d_in[15];
    const float* W3  = (const float*)d_in[16];
    const float* b3  = (const float*)d_in[17];
    float* rating = (float*)d_out;

    // Workspace (~211 MB, under proven-safe 214 MB):
    //   Q [N,256] bf16 (becomes `out` in-place)   51.2 MB
    //   K,V,S [N,256] bf16                       153.6 MB
    //   rp, deg, cursor [N] int                    1.2 MB
    //   csr_src, csr_dst, csr_eid [E] int          4.8 MB
    //   bsum[128]; Wp 256 KB; W1p 128 KB; W2p 16 KB
    unsigned short* Q = (unsigned short*)d_ws;
    const size_t NHDe = (size_t)N_NODES * HD;   // 25.6M elements
    unsigned short* K = Q + NHDe;
    unsigned short* V = K + NHDe;
    unsigned short* S = V + NHDe;
    int* rp      = (int*)(S + NHDe);
    int* deg     = rp + N_NODES;
    int* cursor  = deg + N_NODES;
    int* csr_src = cursor + N_NODES;
    int* csr_dst = csr_src + N_EDGES;
    int* csr_eid = csr_dst + N_EDGES;
    int* bsum    = csr_eid + N_EDGES;
    unsigned short* Wp  = (unsigned short*)(bsum + 128);
    unsigned short* W1p = Wp + 16384 * 8;
    unsigned short* W2p = W1p + 8192 * 8;

    const int nblk  = (N_NODES + 255) / 256;
    const int eblk  = (N_EDGES + 255) / 256;
    const int wgrid = (N_NODES + 3) / 4;

    // CSR build + weight packing
    init_zero<<<nblk, 256, 0, stream>>>(deg, cursor);
    k_deg<<<eblk, 256, 0, stream>>>(ei, deg);
    k_scan1<<<NB_SCAN, 256, 0, stream>>>(deg, rp, bsum);
    k_scan2<<<1, 256, 0, stream>>>(bsum);
    k_scan3<<<nblk, 256, 0, stream>>>(rp, bsum);
    k_bucket<<<eblk, 256, 0, stream>>>(ei, rp, cursor, csr_src, csr_dst, csr_eid);
    pack_wg<<<64, 256, 0, stream>>>(Wq, Wk, Wv, Ws, Wp);
    pack_w1<<<32, 256, 0, stream>>>(W1, W1p);
    pack_w2<<<4, 256, 0, stream>>>(W2, W2p);

    // projections (q/k/v/skip) -> bf16 tables; z split across grid.y
    gemm_proj<<<dim3((N_NODES + 63) / 64, 4), 256, 0, stream>>>(
        x, mem, Wp, bq, bk, bv, bs, Q, K, V, S);

    // fused online-softmax attention; out (bf16) overwrites Q
    k_attn<<<wgrid, 256, 0, stream>>>(rp, deg, csr_src, Q, K, V, S, Q);

    // rating MLP (MFMA) in CSR order
    edge_mlp_mfma<<<N_EDGES / 64, 256, 0, stream>>>(
        csr_src, csr_dst, csr_eid, Q, W1p, b1, W2p, b2, W3, b3, rating);
}

// Round 9
// 499.708 us; speedup vs baseline: 1.1750x; 1.1750x over previous
//
#include <hip/hip_runtime.h>
#include <math.h>

#define N_NODES 100000
#define N_EDGES 400000
#define HID 128
#define HEADS 4
#define OUT_C 64
#define HD 256   // HEADS*OUT_C
#define SCAN_CHUNK 1024
#define NB_SCAN ((N_NODES + SCAN_CHUNK - 1) / SCAN_CHUNK)   // 98

typedef __attribute__((ext_vector_type(8))) short bf16x8;   // 8 bf16 = 4 VGPRs
typedef __attribute__((ext_vector_type(4))) float f32x4;

// fp32 -> bf16 round-to-nearest-even
__device__ __forceinline__ unsigned short fbf(float f) {
    unsigned u = __float_as_uint(f);
    unsigned r = (u + 0x7fffu + ((u >> 16) & 1u)) >> 16;
    return (unsigned short)r;
}
__device__ __forceinline__ float bf2f(unsigned short u) {
    return __uint_as_float(((unsigned)u) << 16);
}

// ---------- K0: zero deg + cursor ----------
__global__ __launch_bounds__(256) void init_zero(int* __restrict__ deg,
                                                 int* __restrict__ cursor) {
    int i = blockIdx.x * 256 + threadIdx.x;
    if (i < N_NODES) { deg[i] = 0; cursor[i] = 0; }
}

// ---------- CSR build: degree count ----------
__global__ __launch_bounds__(256) void k_deg(const int* __restrict__ ei,
                                             int* __restrict__ deg) {
    int e = blockIdx.x * 256 + threadIdx.x;
    if (e < N_EDGES) atomicAdd(&deg[ei[N_EDGES + e]], 1);
}

// ---------- scan 1 ----------
__global__ __launch_bounds__(256) void k_scan1(const int* __restrict__ deg,
                                               int* __restrict__ rp,
                                               int* __restrict__ bsum) {
    __shared__ int ts[256];
    int b = blockIdx.x, t = threadIdx.x;
    int base = b * SCAN_CHUNK + t * 4;
    int vv[4];
    int s = 0;
#pragma unroll
    for (int i = 0; i < 4; ++i) {
        int d = (base + i < N_NODES) ? deg[base + i] : 0;
        vv[i] = s;
        s += d;
    }
    ts[t] = s;
    __syncthreads();
    for (int off = 1; off < 256; off <<= 1) {
        int x = (t >= off) ? ts[t - off] : 0;
        __syncthreads();
        ts[t] += x;
        __syncthreads();
    }
    int ex = ts[t] - s;
#pragma unroll
    for (int i = 0; i < 4; ++i)
        if (base + i < N_NODES) rp[base + i] = ex + vv[i];
    if (t == 255) bsum[b] = ts[255];
}

// ---------- scan 2 ----------
__global__ __launch_bounds__(256) void k_scan2(int* __restrict__ bsum) {
    __shared__ int ts[256];
    int t = threadIdx.x;
    int v = (t < NB_SCAN) ? bsum[t] : 0;
    ts[t] = v;
    __syncthreads();
    for (int off = 1; off < 256; off <<= 1) {
        int x = (t >= off) ? ts[t - off] : 0;
        __syncthreads();
        ts[t] += x;
        __syncthreads();
    }
    if (t < NB_SCAN) bsum[t] = ts[t] - v;
}

// ---------- scan 3 ----------
__global__ __launch_bounds__(256) void k_scan3(int* __restrict__ rp,
                                               const int* __restrict__ bsum) {
    int i = blockIdx.x * 256 + threadIdx.x;
    if (i < N_NODES) rp[i] += bsum[i / SCAN_CHUNK];
}

// ---------- bucket: fill csr_src / csr_dst / csr_eid ----------
__global__ __launch_bounds__(256) void k_bucket(const int* __restrict__ ei,
                                                const int* __restrict__ rp,
                                                int* __restrict__ cursor,
                                                int* __restrict__ csr_src,
                                                int* __restrict__ csr_dst,
                                                int* __restrict__ csr_eid) {
    int e = blockIdx.x * 256 + threadIdx.x;
    if (e >= N_EDGES) return;
    int src = ei[e];
    int d   = ei[N_EDGES + e];
    int idx = atomicAdd(&cursor[d], 1);
    int s   = rp[d] + idx;
    csr_src[s] = src;
    csr_dst[s] = d;
    csr_eid[s] = e;
}

// ---------- pack 4 projection weights [128,256] -> [z][kt][nt][lane][8] bf16 ----------
__global__ __launch_bounds__(256) void pack_wg(
    const float* __restrict__ Wq, const float* __restrict__ Wk,
    const float* __restrict__ Wv, const float* __restrict__ Ws,
    unsigned short* __restrict__ Wp) {
    int i = blockIdx.x * 256 + threadIdx.x;   // 4*4*16*64 = 16384
    if (i >= 16384) return;
    int lane = i & 63, nt = (i >> 6) & 15, kt = (i >> 10) & 3, z = i >> 12;
    const float* W = (z == 0) ? Wq : (z == 1) ? Wk : (z == 2) ? Wv : Ws;
    int q = lane >> 4, c = lane & 15;
#pragma unroll
    for (int j = 0; j < 8; ++j)
        Wp[i * 8 + j] = fbf(W[(kt * 32 + q * 8 + j) * HD + nt * 16 + c]);
}

// ---------- pack fused PD weight: Wc[256k][256n], n<128 -> W1_top, else W1_bot ----------
// frag order [kt(8)][nt(16)][lane][8]
__global__ __launch_bounds__(256) void pack_wc(const float* __restrict__ W1,
                                               unsigned short* __restrict__ Wcp) {
    int i = blockIdx.x * 256 + threadIdx.x;   // 8*16*64 = 8192
    if (i >= 8192) return;
    int lane = i & 63, nt = (i >> 6) & 15, kt = i >> 10;
    int q = lane >> 4, c = lane & 15;
    int n = nt * 16 + c;
#pragma unroll
    for (int j = 0; j < 8; ++j) {
        int k = kt * 32 + q * 8 + j;
        float v = (n < 128) ? W1[k * 128 + n] : W1[(k + 256) * 128 + (n - 128)];
        Wcp[i * 8 + j] = fbf(v);
    }
}

// ---------- pack W2 [128,64] -> [kt][nt][lane][8] bf16 ----------
__global__ __launch_bounds__(256) void pack_w2(const float* __restrict__ W2,
                                               unsigned short* __restrict__ W2p) {
    int i = blockIdx.x * 256 + threadIdx.x;   // 4*4*64 = 1024
    if (i >= 1024) return;
    int lane = i & 63, nt = (i >> 6) & 3, kt = i >> 8;
    int q = lane >> 4, c = lane & 15;
#pragma unroll
    for (int j = 0; j < 8; ++j)
        W2p[i * 8 + j] = fbf(W2[(kt * 32 + q * 8 + j) * 64 + nt * 16 + c]);
}

// ---------- K1: fused projection GEMM (MFMA bf16), per-wave output slabs (R7 form) ----------
__global__ __launch_bounds__(256) void gemm_proj(
    const float* __restrict__ x, const float* __restrict__ mem,
    const unsigned short* __restrict__ Wp,
    const float* __restrict__ bq, const float* __restrict__ bk,
    const float* __restrict__ bv, const float* __restrict__ bs,
    unsigned short* __restrict__ Q, unsigned short* __restrict__ K,
    unsigned short* __restrict__ V, unsigned short* __restrict__ S)
{
    __shared__ __align__(16) short As[64 * 136];      // bf16(x+mem), pad 136
    __shared__ __align__(16) short Slab[4 * 64 * 68]; // per-wave 64x68 slabs

    const int t = threadIdx.x;
    const int w = t >> 6, l = t & 63;
    const int q = l >> 4, c = l & 15;
    const int m0 = blockIdx.x * 64;

    {
        const float4* x4 = (const float4*)x;
        const float4* m4 = (const float4*)mem;
#pragma unroll
        for (int j = 0; j < 8; ++j) {
            int idx = t + j * 256;
            int row = idx >> 5, c4 = idx & 31;
            int gr  = m0 + row;
            ushort4 hv = make_ushort4(0, 0, 0, 0);
            if (gr < N_NODES) {
                float4 a = x4[(size_t)gr * 32 + c4];
                float4 b = m4[(size_t)gr * 32 + c4];
                hv = make_ushort4(fbf(a.x + b.x), fbf(a.y + b.y),
                                  fbf(a.z + b.z), fbf(a.w + b.w));
            }
            *(ushort4*)&As[row * 136 + c4 * 4] = hv;
        }
    }
    __syncthreads();

    short* slab = &Slab[w * 64 * 68];
    const int srow = l >> 3;
    const int schk = l & 7;

    for (int z = 0; z < 4; ++z) {
        const float* bz = (z == 0) ? bq : (z == 1) ? bk : (z == 2) ? bv : bs;
        unsigned short* Oz = (z == 0) ? Q : (z == 1) ? K : (z == 2) ? V : S;

        f32x4 acc[4][4];
#pragma unroll
        for (int mt = 0; mt < 4; ++mt)
#pragma unroll
            for (int nt = 0; nt < 4; ++nt) acc[mt][nt] = (f32x4){0.f, 0.f, 0.f, 0.f};

#pragma unroll
        for (int kt = 0; kt < 4; ++kt) {
            bf16x8 af[4];
#pragma unroll
            for (int mt = 0; mt < 4; ++mt)
                af[mt] = *(const bf16x8*)&As[(mt * 16 + c) * 136 + kt * 32 + q * 8];
#pragma unroll
            for (int nt = 0; nt < 4; ++nt) {
                int ntg = w * 4 + nt;
                bf16x8 bv8 = *(const bf16x8*)&Wp[(size_t)(((z * 4 + kt) * 16 + ntg) * 64 + l) * 8];
#pragma unroll
                for (int mt = 0; mt < 4; ++mt)
                    acc[mt][nt] = __builtin_amdgcn_mfma_f32_16x16x32_bf16(af[mt], bv8, acc[mt][nt], 0, 0, 0);
            }
        }

#pragma unroll
        for (int nt = 0; nt < 4; ++nt) {
            float bb = bz[w * 64 + nt * 16 + c];
#pragma unroll
            for (int mt = 0; mt < 4; ++mt)
#pragma unroll
                for (int r = 0; r < 4; ++r)
                    slab[(mt * 16 + q * 4 + r) * 68 + nt * 16 + c] =
                        (short)fbf(acc[mt][nt][r] + bb);
        }
#pragma unroll
        for (int j = 0; j < 8; ++j) {
            int row = j * 8 + srow;
            int gr = m0 + row;
            if (gr < N_NODES)
                *(bf16x8*)&Oz[(size_t)gr * HD + w * 64 + schk * 8] =
                    *(const bf16x8*)&slab[row * 68 + schk * 8];
        }
    }
}

// ---------- K2: fused attention, online softmax, one wave per node ----------
__global__ __launch_bounds__(256) void k_attn(
    const int* __restrict__ rp, const int* __restrict__ deg,
    const int* __restrict__ csr_src,
    const unsigned short* __restrict__ Q, const unsigned short* __restrict__ K,
    const unsigned short* __restrict__ V, const unsigned short* __restrict__ S,
    unsigned short* __restrict__ out)
{
    int node = blockIdx.x * 4 + (threadIdx.x >> 6);
    int l = threadIdx.x & 63;
    if (node >= N_NODES) return;
    int start = rp[node];
    int cnt   = deg[node];

    float q0, q1, q2, q3;
    {
        ushort4 u = *(const ushort4*)&Q[(size_t)node * HD + l * 4];
        q0 = bf2f(u.x); q1 = bf2f(u.y); q2 = bf2f(u.z); q3 = bf2f(u.w);
    }

    float m = -1e30f, d = 0.f;
    float a0 = 0.f, a1 = 0.f, a2 = 0.f, a3 = 0.f;

    for (int i = 0; i < cnt; ++i) {
        int src = csr_src[start + i];
        ushort4 ku = *(const ushort4*)&K[(size_t)src * HD + l * 4];
        float s = q0 * bf2f(ku.x) + q1 * bf2f(ku.y) + q2 * bf2f(ku.z) + q3 * bf2f(ku.w);
        s += __shfl_xor(s, 1);
        s += __shfl_xor(s, 2);
        s += __shfl_xor(s, 4);
        s += __shfl_xor(s, 8);
        s *= 0.125f;                       // 1/sqrt(64)

        float mn    = fmaxf(m, s);
        float scale = __expf(m - mn);
        float e     = __expf(s - mn);
        d = d * scale + e;
        ushort4 vu = *(const ushort4*)&V[(size_t)src * HD + l * 4];
        a0 = a0 * scale + e * bf2f(vu.x);
        a1 = a1 * scale + e * bf2f(vu.y);
        a2 = a2 * scale + e * bf2f(vu.z);
        a3 = a3 * scale + e * bf2f(vu.w);
        m = mn;
    }

    float inv = 1.f / (d + 1e-16f);
    ushort4 su = *(const ushort4*)&S[(size_t)node * HD + l * 4];
    ushort4 ov = make_ushort4(fbf(bf2f(su.x) + a0 * inv),
                              fbf(bf2f(su.y) + a1 * inv),
                              fbf(bf2f(su.z) + a2 * inv),
                              fbf(bf2f(su.w) + a3 * inv));
    *(ushort4*)&out[(size_t)node * HD + l * 4] = ov;
}

// ---------- K3: PD GEMM — PD[n] = out[n] @ [W1_top | W1_bot],  M=100k K=256 N=256 ----------
__global__ __launch_bounds__(256) void pd_gemm(
    const unsigned short* __restrict__ outb,
    const unsigned short* __restrict__ Wcp,
    unsigned short* __restrict__ PD)
{
    __shared__ __align__(16) char sh[4 * 64 * 68 * 2];   // 34816 B union
    short* As   = (short*)sh;                            //   As [64][264]  (33792 B)
    short* Slab = (short*)sh;                            //   Slab 4x[64][68]

    const int t = threadIdx.x;
    const int w = t >> 6, l = t & 63;
    const int q = l >> 4, c = l & 15;
    const int m0 = blockIdx.x * 64;

    // stage A = out[m0..m0+64, 0..256) bf16
#pragma unroll
    for (int j = 0; j < 8; ++j) {
        int idx = t + j * 256;           // 2048 chunks of 16 B
        int row = idx >> 5, c4 = idx & 31;
        int gr  = m0 + row;
        bf16x8 v = (bf16x8){0,0,0,0,0,0,0,0};
        if (gr < N_NODES)
            v = *(const bf16x8*)&outb[(size_t)gr * HD + c4 * 8];
        *(bf16x8*)&As[row * 264 + c4 * 8] = v;
    }
    __syncthreads();

    f32x4 acc[4][4];
#pragma unroll
    for (int mt = 0; mt < 4; ++mt)
#pragma unroll
        for (int nt = 0; nt < 4; ++nt) acc[mt][nt] = (f32x4){0.f, 0.f, 0.f, 0.f};

#pragma unroll
    for (int kt = 0; kt < 8; ++kt) {
        bf16x8 af[4];
#pragma unroll
        for (int mt = 0; mt < 4; ++mt)
            af[mt] = *(const bf16x8*)&As[(mt * 16 + c) * 264 + kt * 32 + q * 8];
#pragma unroll
        for (int nt = 0; nt < 4; ++nt) {
            int ntg = w * 4 + nt;
            bf16x8 bv8 = *(const bf16x8*)&Wcp[(size_t)((kt * 16 + ntg) * 64 + l) * 8];
#pragma unroll
            for (int mt = 0; mt < 4; ++mt)
                acc[mt][nt] = __builtin_amdgcn_mfma_f32_16x16x32_bf16(af[mt], bv8, acc[mt][nt], 0, 0, 0);
        }
    }
    __syncthreads();   // all As reads done; Slab aliases As

    short* slab = &Slab[w * 64 * 68];
#pragma unroll
    for (int nt = 0; nt < 4; ++nt)
#pragma unroll
        for (int mt = 0; mt < 4; ++mt)
#pragma unroll
            for (int r = 0; r < 4; ++r)
                slab[(mt * 16 + q * 4 + r) * 68 + nt * 16 + c] =
                    (short)fbf(acc[mt][nt][r]);
    const int srow = l >> 3, schk = l & 7;
#pragma unroll
    for (int j = 0; j < 8; ++j) {
        int row = j * 8 + srow;
        int gr = m0 + row;
        if (gr < N_NODES)
            *(bf16x8*)&PD[(size_t)gr * HD + w * 64 + schk * 8] =
                *(const bf16x8*)&slab[row * 68 + schk * 8];
    }
}

// ---------- K5: light edge MLP — h1 = relu(P[src]+D[dst]+b1); layer2 MFMA; layer3 ----------
__global__ __launch_bounds__(256) void edge_mlp_pd(
    const int* __restrict__ csr_src, const int* __restrict__ csr_dst,
    const int* __restrict__ csr_eid,
    const unsigned short* __restrict__ PD,
    const float* __restrict__ b1,
    const unsigned short* __restrict__ W2p, const float* __restrict__ b2,
    const float* __restrict__ W3, const float* __restrict__ b3,
    float* __restrict__ rating)
{
    __shared__ __align__(16) char lds[64 * 136 * 2];   // 17408 B union:
    short* h1t = (short*)lds;                          //   h1 bf16 [64][136]
    float* h2s = (float*)lds;                          //   h2 f32 [64][65] (aliases after barrier)

    const int t = threadIdx.x;
    const int w = t >> 6, l = t & 63;
    const int q = l >> 4, c = l & 15;
    const int e0 = blockIdx.x * 64;

    // stage h1 = relu(P[src] + D[dst] + b1): 64 rows x 128 cols bf16
#pragma unroll
    for (int j = 0; j < 4; ++j) {
        int idx = t + j * 256;          // 1024 chunks of 8 elems
        int row = idx >> 4, ch = idx & 15;
        int src = csr_src[e0 + row];
        int dst = csr_dst[e0 + row];
        bf16x8 pv = *(const bf16x8*)&PD[(size_t)src * HD + ch * 8];
        bf16x8 dv = *(const bf16x8*)&PD[(size_t)dst * HD + 128 + ch * 8];
        float4 ba = *(const float4*)&b1[ch * 8];
        float4 bb = *(const float4*)&b1[ch * 8 + 4];
        bf16x8 hv;
        hv[0] = (short)fbf(fmaxf(bf2f((unsigned short)pv[0]) + bf2f((unsigned short)dv[0]) + ba.x, 0.f));
        hv[1] = (short)fbf(fmaxf(bf2f((unsigned short)pv[1]) + bf2f((unsigned short)dv[1]) + ba.y, 0.f));
        hv[2] = (short)fbf(fmaxf(bf2f((unsigned short)pv[2]) + bf2f((unsigned short)dv[2]) + ba.z, 0.f));
        hv[3] = (short)fbf(fmaxf(bf2f((unsigned short)pv[3]) + bf2f((unsigned short)dv[3]) + ba.w, 0.f));
        hv[4] = (short)fbf(fmaxf(bf2f((unsigned short)pv[4]) + bf2f((unsigned short)dv[4]) + bb.x, 0.f));
        hv[5] = (short)fbf(fmaxf(bf2f((unsigned short)pv[5]) + bf2f((unsigned short)dv[5]) + bb.y, 0.f));
        hv[6] = (short)fbf(fmaxf(bf2f((unsigned short)pv[6]) + bf2f((unsigned short)dv[6]) + bb.z, 0.f));
        hv[7] = (short)fbf(fmaxf(bf2f((unsigned short)pv[7]) + bf2f((unsigned short)dv[7]) + bb.w, 0.f));
        *(bf16x8*)&h1t[row * 136 + ch * 8] = hv;
    }
    __syncthreads();

    // layer2 MFMA: [64,128] @ [128,64]
    f32x4 acc2[4];
#pragma unroll
    for (int i = 0; i < 4; ++i) acc2[i] = (f32x4){0.f, 0.f, 0.f, 0.f};
#pragma unroll
    for (int kt = 0; kt < 4; ++kt) {
        bf16x8 av = *(const bf16x8*)&h1t[(w * 16 + c) * 136 + kt * 32 + q * 8];
#pragma unroll
        for (int nt = 0; nt < 4; ++nt) {
            bf16x8 bv = *(const bf16x8*)&W2p[(size_t)((kt * 4 + nt) * 64 + l) * 8];
            acc2[nt] = __builtin_amdgcn_mfma_f32_16x16x32_bf16(av, bv, acc2[nt], 0, 0, 0);
        }
    }
    __syncthreads();   // h1 reads done; h2 aliases

#pragma unroll
    for (int nt = 0; nt < 4; ++nt) {
        float bv = b2[nt * 16 + c];
#pragma unroll
        for (int r = 0; r < 4; ++r)
            h2s[(w * 16 + q * 4 + r) * 65 + nt * 16 + c] = fmaxf(acc2[nt][r] + bv, 0.f);
    }
    __syncthreads();

    if (t < 64) {
        float a = b3[0];
#pragma unroll 8
        for (int kk = 0; kk < 64; ++kk)
            a += h2s[t * 65 + kk] * W3[kk];
        rating[csr_eid[e0 + t]] = 4.f / (1.f + __expf(-a)) + 1.f;
    }
}

extern "C" void kernel_launch(void* const* d_in, const int* in_sizes, int n_in,
                              void* d_out, int out_size, void* d_ws, size_t ws_size,
                              hipStream_t stream) {
    const int*   ei  = (const int*)d_in[0];    // [2, E]
    const float* x   = (const float*)d_in[2];
    const float* mem = (const float*)d_in[3];
    const float* Wq  = (const float*)d_in[4];
    const float* bq  = (const float*)d_in[5];
    const float* Wk  = (const float*)d_in[6];
    const float* bk  = (const float*)d_in[7];
    const float* Wv  = (const float*)d_in[8];
    const float* bv  = (const float*)d_in[9];
    const float* Ws  = (const float*)d_in[10];
    const float* bs  = (const float*)d_in[11];
    const float* W1  = (const float*)d_in[12];
    const float* b1  = (const float*)d_in[13];
    const float* W2  = (const float*)d_in[14];
    const float* b2  = (const float*)d_in[15];
    const float* W3  = (const float*)d_in[16];
    const float* b3  = (const float*)d_in[17];
    float* rating = (float*)d_out;

    // Workspace (~211 MB):
    //   Q [N,256] bf16 (becomes `out`)            51.2 MB
    //   K [N,256] bf16 (becomes PD after attn)    51.2 MB
    //   V,S [N,256] bf16                         102.4 MB
    //   rp, deg, cursor, csr_* , bsum, packs       ~6.5 MB
    unsigned short* Q = (unsigned short*)d_ws;
    const size_t NHDe = (size_t)N_NODES * HD;   // 25.6M elements
    unsigned short* K = Q + NHDe;
    unsigned short* V = K + NHDe;
    unsigned short* S = V + NHDe;
    int* rp      = (int*)(S + NHDe);
    int* deg     = rp + N_NODES;
    int* cursor  = deg + N_NODES;
    int* csr_src = cursor + N_NODES;
    int* csr_dst = csr_src + N_EDGES;
    int* csr_eid = csr_dst + N_EDGES;
    int* bsum    = csr_eid + N_EDGES;
    unsigned short* Wp  = (unsigned short*)(bsum + 128);
    unsigned short* Wcp = Wp + 16384 * 8;
    unsigned short* W2p = Wcp + 8192 * 8;
    unsigned short* PD  = K;   // K table dead after attention

    const int nblk  = (N_NODES + 255) / 256;
    const int eblk  = (N_EDGES + 255) / 256;
    const int wgrid = (N_NODES + 3) / 4;

    // CSR build + weight packing
    init_zero<<<nblk, 256, 0, stream>>>(deg, cursor);
    k_deg<<<eblk, 256, 0, stream>>>(ei, deg);
    k_scan1<<<NB_SCAN, 256, 0, stream>>>(deg, rp, bsum);
    k_scan2<<<1, 256, 0, stream>>>(bsum);
    k_scan3<<<nblk, 256, 0, stream>>>(rp, bsum);
    k_bucket<<<eblk, 256, 0, stream>>>(ei, rp, cursor, csr_src, csr_dst, csr_eid);
    pack_wg<<<64, 256, 0, stream>>>(Wq, Wk, Wv, Ws, Wp);
    pack_wc<<<32, 256, 0, stream>>>(W1, Wcp);
    pack_w2<<<4, 256, 0, stream>>>(W2, W2p);

    // projections (q/k/v/skip) -> bf16 tables
    gemm_proj<<<(N_NODES + 63) / 64, 256, 0, stream>>>(
        x, mem, Wp, bq, bk, bv, bs, Q, K, V, S);

    // fused online-softmax attention; out (bf16) overwrites Q
    k_attn<<<wgrid, 256, 0, stream>>>(rp, deg, csr_src, Q, K, V, S, Q);

    // node-level PD GEMM (layer-1 factorization); PD overwrites K
    pd_gemm<<<(N_NODES + 63) / 64, 256, 0, stream>>>(Q, Wcp, PD);

    // light edge MLP in CSR order
    edge_mlp_pd<<<N_EDGES / 64, 256, 0, stream>>>(
        csr_src, csr_dst, csr_eid, PD, b1, W2p, b2, W3, b3, rating);
}